// Round 1
// baseline (150.470 us; speedup 1.0000x reference)
//
#include <hip/hip_runtime.h>

// Problem constants
#define B_    1024
#define C_    128
#define ELL   16
#define EQ    3
#define E_    10
#define P3    23
#define P2    5
#define NSEG  176            // padded segment row: 16 f4-aligned v-segments
#define RSTR  180            // row stride (180%32=20 -> 8 bank-starts x2 = 2-way, free)
#define SRS   (48 * RSTR)    // 8640 floats per (e,c) S-slice
#define KD    28             // folded weight depth: 23 (wmax) + 5 (w2)

// ws layout (bytes)
#define WS_CNT   0
#define WS_LIST  64
#define WS_S     65536       // S slices: 10*128*8640*4 = 44.2 MB (ws >= 66 MB, r1-r9)

// segment offsets: v-th segment holds [lin_v, Q_vv, Q_v,v+1, .., Q_v,15, pad0s]
// lengths (real) 17-v, padded to x4: {20,16,16,16,16,12,12,12,12,8,8,8,8,4,4,4}
#define SEG_OFF_INIT {0,20,36,52,68,84,96,108,120,132,140,148,156,164,168,172}

// ---------------------------------------------------------------------------
// Bucketing: bucket batch indices by element, pad each bucket to x64 by
// replicating the last real index (k_main then needs no load guards).
__device__ void do_lists(const float* __restrict__ y, int* __restrict__ cnt_g,
                         int* __restrict__ list_g, int t) {
    __shared__ int lcnt[E_];
    if (t < E_) lcnt[t] = 0;
    __syncthreads();
    for (int r = 0; r < 4; ++r) {
        int b = t + 256 * r;
        int e = 0;
        #pragma unroll
        for (int j = 1; j < E_; ++j)
            if (y[b * E_ + j] > 0.5f) e = j;
        int slot = atomicAdd(&lcnt[e], 1);
        list_g[e * B_ + slot] = b;
    }
    __syncthreads();
    if (t < E_) {
        int c0 = lcnt[t];
        cnt_g[t] = c0;
        int last = (c0 > 0) ? list_g[t * B_ + c0 - 1] : 0;
        int cp = (c0 + 63) & ~63;
        if (cp > B_) cp = B_;
        for (int s2 = c0; s2 < cp; ++s2) list_g[t * B_ + s2] = last;
    }
}

// ---------------------------------------------------------------------------
// k_s: build segment-layout S rows (UNCHANGED from verified r11/r12 version):
//  slot (v,0)   : lin_v  = sum_q U2[j,v,q]  * w2[e,q,c]
//  slot (v,l>0) : Q_v,i  = sum_k (U3[j,v,i,k] + (i!=v)*U3[j,i,v,k]) * wmax[e,k,c]
//                 with i = v+l-1; pad slots = 0.
__global__ __launch_bounds__(256, 2) void k_s(const float* __restrict__ U3,
                                              const float* __restrict__ U2,
                                              const float* __restrict__ wmax,
                                              const float* __restrict__ w2,
                                              const float* __restrict__ y,
                                              float* __restrict__ Sg,
                                              int* __restrict__ cnt_g,
                                              int* __restrict__ list_g) {
    const int t = threadIdx.x;
    if (blockIdx.x == 48) {
        if (blockIdx.y == 0 && blockIdx.z == 0) do_lists(y, cnt_g, list_g, t);
        return;
    }
    __shared__ __align__(16) float U3L[ELL * ELL * P3];  // 23,552 B
    __shared__ __align__(16) float wsm[KD * 32];         //  3,584 B

    const int j  = blockIdx.x;
    const int e  = blockIdx.y;
    const int cq = blockIdx.z;

    // stage U3[j] (5888 floats = 1472 f4), fully coalesced
    {
        const float4* src4 = (const float4*)(U3 + (size_t)j * (ELL * ELL * P3));
        float4* dst4 = (float4*)U3L;
        for (int f = t; f < 1472; f += 256) dst4[f] = src4[f];
    }
    // folded weight table (23 wmax + 5 w2) for this (e, c-quarter)
    for (int idx = t; idx < KD * 32; idx += 256) {
        int k = idx >> 5, cc = idx & 31, c = cq * 32 + cc;
        wsm[idx] = (k < 23) ? wmax[(e * P3 + k) * C_ + c]
                            : w2[(e * P2 + (k - 23)) * C_ + c];
    }
    __syncthreads();

    if (t >= NSEG) return;

    const int SO[16] = SEG_OFF_INIT;
    int v = 0;
    #pragma unroll
    for (int s = 1; s < 16; ++s) v += (t >= SO[s]) ? 1 : 0;
    const int l    = t - SO[v];
    const int real = 17 - v;           // slot count incl. lin

    float sk[P3], skl[P2];
    #pragma unroll
    for (int k = 0; k < P3; ++k) sk[k] = 0.f;
    #pragma unroll
    for (int q = 0; q < P2; ++q) skl[q] = 0.f;

    if (l == 0) {
        #pragma unroll
        for (int q = 0; q < P2; ++q)
            skl[q] = U2[(size_t)j * (ELL * P2) + v * P2 + q];
    } else if (l < real) {
        int i = v + l - 1;
        const float* pa = &U3L[(v * ELL + i) * P3];
        const float* pb = &U3L[(i * ELL + v) * P3];
        if (i != v) {
            #pragma unroll
            for (int k = 0; k < P3; ++k) sk[k] = pa[k] + pb[k];
        } else {
            #pragma unroll
            for (int k = 0; k < P3; ++k) sk[k] = pa[k];
        }
    }   // else: pad slot -> stays zero

    #pragma unroll
    for (int g = 0; g < 8; ++g) {
        float a[4] = {0.f, 0.f, 0.f, 0.f};
        #pragma unroll
        for (int k = 0; k < P3; ++k) {
            float4 wk = *(const float4*)&wsm[k * 32 + 4 * g];
            a[0] += sk[k] * wk.x; a[1] += sk[k] * wk.y;
            a[2] += sk[k] * wk.z; a[3] += sk[k] * wk.w;
        }
        #pragma unroll
        for (int q = 0; q < P2; ++q) {
            float4 wk = *(const float4*)&wsm[(23 + q) * 32 + 4 * g];
            a[0] += skl[q] * wk.x; a[1] += skl[q] * wk.y;
            a[2] += skl[q] * wk.z; a[3] += skl[q] * wk.w;
        }
        #pragma unroll
        for (int q2 = 0; q2 < 4; ++q2) {
            int c = cq * 32 + g * 4 + q2;
            Sg[(size_t)(e * C_ + c) * SRS + j * RSTR + t] = a[q2];
        }
    }
}

// ---------------------------------------------------------------------------
// k_main helpers (r13): pad-trimmed v-loop + two-chunk pipelined body.
//
// chunk_load: 4 batch rows -> registers. xm is [4][16] now (pads eliminated:
// every FMA against a known-zero pad coefficient is trimmed at compile time).
__device__ __forceinline__ void chunk_load(const float* __restrict__ x,
                                           const int* __restrict__ list_g,
                                           int e, int c, int xx, int slot,
                                           int (&bidx)[4], float (&xm)[4][16],
                                           float (&xo)[4]) {
    #pragma unroll
    for (int r = 0; r < 4; ++r) bidx[r] = list_g[e * B_ + slot + r];
    #pragma unroll
    for (int r = 0; r < 4; ++r) {
        const float* xb = x + ((size_t)bidx[r] * C_ + c) * ELL;
        #pragma unroll
        for (int i4 = 0; i4 < 4; ++i4) {
            float4 a = ((const float4*)xb)[i4];
            xm[r][4 * i4 + 0] = a.x; xm[r][4 * i4 + 1] = a.y;
            xm[r][4 * i4 + 2] = a.z; xm[r][4 * i4 + 3] = a.w;
        }
        xo[r] = xb[xx];   // own-x element (L1 hit; no dynamic reg index)
    }
}

// vloop: t2 += sum_v x_v*(lin_v + sum_{i>=v} Q_vi*x_i), pad terms skipped.
// All index guards are compile-time constants after full unroll; skipped
// terms multiplied zero coefficients in the old code (bit-identical result).
__device__ __forceinline__ void vloop(const float* __restrict__ v3p,
                                      const float (&xm)[4][16],
                                      float (&t2)[4]) {
    const int SO[16] = SEG_OFF_INIT;
    #pragma unroll
    for (int v = 0; v < 16; ++v) {
        const int off = SO[v];
        const int nf4 = (v == 0) ? 5 : (v < 5) ? 4 : (v < 9) ? 3 : (v < 13) ? 2 : 1;
        float inner[4];
        {   // first f4: [lin, Q_vv, Q_v,v+1, Q_v,v+2]
            float4 u = *(const float4*)(v3p + off);
            #pragma unroll
            for (int r = 0; r < 4; ++r) {
                float s = u.x + u.y * xm[r][v];
                if (v + 1 <= 15) s += u.z * xm[r][v + 1];
                if (v + 2 <= 15) s += u.w * xm[r][v + 2];
                inner[r] = s;
            }
        }
        #pragma unroll
        for (int q = 1; q < nf4; ++q) {
            float4 u = *(const float4*)(v3p + off + 4 * q);
            const int i0 = v + 4 * q - 1;
            #pragma unroll
            for (int r = 0; r < 4; ++r) {
                inner[r] += u.x * xm[r][i0];
                if (i0 + 1 <= 15) inner[r] += u.y * xm[r][i0 + 1];
                if (i0 + 2 <= 15) inner[r] += u.z * xm[r][i0 + 2];
                if (i0 + 3 <= 15) inner[r] += u.w * xm[r][i0 + 3];
            }
        }
        #pragma unroll
        for (int r = 0; r < 4; ++r) t2[r] += xm[r][v] * inner[r];
    }
}

// chunk_tail: out[b,c,w] = sum_xx (t2 + v1[xx]) * x[xx]  (width-16 butterfly)
__device__ __forceinline__ void chunk_tail(const float (&t2)[4],
                                           const float (&xo)[4],
                                           const int (&bidx)[4],
                                           int slot, int cnt, float v1x,
                                           int xx, int c, int w,
                                           float* __restrict__ out) {
    float cv[4];
    #pragma unroll
    for (int r = 0; r < 4; ++r) cv[r] = (t2[r] + v1x) * xo[r];
    #pragma unroll
    for (int m = 1; m < 16; m <<= 1) {
        #pragma unroll
        for (int r = 0; r < 4; ++r) cv[r] += __shfl_xor(cv[r], m, 16);
    }
    if (xx == 0) {
        #pragma unroll
        for (int r = 0; r < 4; ++r)
            if (slot + r < cnt)
                out[(size_t)bidx[r] * (C_ * EQ) + c * EQ + w] = cv[r];
    }
}

// ---------------------------------------------------------------------------
// k_main r13: grid (C_*EQ, E_), 256 threads; bx = c*3+w.
// xx = t&15 (row within w), bs = t>>4; 4 batch rows/thread -> chunk = 64.
// Changes vs r12 (139.6us, k_main 46.5us, VALUBusy 83%, conflicts 0):
//  1. pad-trimmed v-loop: 768 -> ~650 FMA/thread-chunk, xm[4][19]->[4][16].
//  2. per-chunk __syncthreads() -> asm memory clobber (same anti-LICM pin at
//     zero runtime cost; no real cross-thread dep exists inside the loop).
//  3. two-chunk pipeline: B's bidx/x loads issue BEFORE A's v-loop so B's
//     ~400cy global-load chain hides under A's compute. The clobber between
//     vloop A and vloop B blocks ds_read CSE across the halves (which would
//     hoist 176 LDS floats live -> the r5/r6 spill blowup).
__global__ __launch_bounds__(256, 2) void k_main(
    const float* __restrict__ x, const float* __restrict__ Sg,
    const float* __restrict__ U1, const float* __restrict__ w1,
    const int* __restrict__ cnt_g, const int* __restrict__ list_g,
    float* __restrict__ out) {

    __shared__ __align__(16) float V3L[16 * RSTR];   // 11,520 B

    const int t  = threadIdx.x;
    const int bx = blockIdx.x;
    const int w  = bx % 3, c = bx / 3;
    const int e  = blockIdx.y;
    const int xx = t & 15, bs = t >> 4;
    const int cnt  = cnt_g[e];
    const int cntp = (cnt + 63) & ~63;

    // ---- fill V3L: this w's 16 rows = 2880 floats = 720 f4, straight copy
    {
        const float4* src = (const float4*)(Sg + (size_t)(e * C_ + c) * SRS
                                            + (size_t)w * 16 * RSTR);
        float4* dst = (float4*)V3L;
        #pragma unroll
        for (int r = 0; r < 2; ++r) dst[t + 256 * r] = src[t + 256 * r];
        if (t < 208) dst[512 + t] = src[512 + t];
    }
    const float v1x = U1[w * 16 + xx] * w1[e * C_ + c];
    __syncthreads();

    const float* v3p = &V3L[xx * RSTR];

    // ---- paired chunk loop: 128 rows per iter, tail body for odd chunk ----
    int base = 0;
    #pragma clang loop unroll(disable)
    for (; base + 128 <= cntp; base += 128) {
        asm volatile("" ::: "memory");   // anti-LICM liveness pin
        const int sA = base + bs * 4;
        const int sB = sA + 64;          // valid: base+128 <= cntp
        int bidxA[4], bidxB[4];
        float xmA[4][16], xmB[4][16], xoA[4], xoB[4];
        chunk_load(x, list_g, e, c, xx, sA, bidxA, xmA, xoA);
        chunk_load(x, list_g, e, c, xx, sB, bidxB, xmB, xoB);

        float t2A[4] = {0.f, 0.f, 0.f, 0.f};
        vloop(v3p, xmA, t2A);
        chunk_tail(t2A, xoA, bidxA, sA, cnt, v1x, xx, c, w, out);

        asm volatile("" ::: "memory");   // block ds_read CSE across halves

        float t2B[4] = {0.f, 0.f, 0.f, 0.f};
        vloop(v3p, xmB, t2B);
        chunk_tail(t2B, xoB, bidxB, sB, cnt, v1x, xx, c, w, out);
    }
    if (base < cntp) {
        asm volatile("" ::: "memory");
        const int sA = base + bs * 4;
        int bidxA[4];
        float xmA[4][16], xoA[4];
        chunk_load(x, list_g, e, c, xx, sA, bidxA, xmA, xoA);
        float t2A[4] = {0.f, 0.f, 0.f, 0.f};
        vloop(v3p, xmA, t2A);
        chunk_tail(t2A, xoA, bidxA, sA, cnt, v1x, xx, c, w, out);
    }
}

// ---------------------------------------------------------------------------
extern "C" void kernel_launch(void* const* d_in, const int* in_sizes, int n_in,
                              void* d_out, int out_size, void* d_ws, size_t ws_size,
                              hipStream_t stream) {
    const float* x    = (const float*)d_in[0];
    const float* y    = (const float*)d_in[1];
    const float* U3   = (const float*)d_in[2];
    const float* U2   = (const float*)d_in[3];
    const float* U1   = (const float*)d_in[4];
    const float* wmax = (const float*)d_in[5];
    const float* w2   = (const float*)d_in[6];
    const float* w1   = (const float*)d_in[7];
    float* out = (float*)d_out;
    char*  ws  = (char*)d_ws;

    int*   cnt_g  = (int*)(ws + WS_CNT);
    int*   list_g = (int*)(ws + WS_LIST);
    float* Sg     = (float*)(ws + WS_S);
    (void)ws_size;   // 44.3 MB needed; harness ws confirmed >= 66 MB (r1-r9)

    k_s<<<dim3(49, E_, 4), 256, 0, stream>>>(U3, U2, wmax, w2, y, Sg, cnt_g, list_g);
    k_main<<<dim3(C_ * EQ, E_), 256, 0, stream>>>(x, Sg, U1, w1, cnt_g, list_g, out);
}

// Round 2
// 135.571 us; speedup vs baseline: 1.1099x; 1.1099x over previous
//
#include <hip/hip_runtime.h>

// Problem constants
#define B_    1024
#define C_    128
#define ELL   16
#define EQ    3
#define E_    10
#define P3    23
#define P2    5
#define NSEG  176            // padded segment row: 16 f4-aligned v-segments
#define RSTR  180            // row stride (180%32=20 -> 8 bank-starts x2 = 2-way, free)
#define SRS   (48 * RSTR)    // 8640 floats per (e,c) S-slice
#define KD    28             // folded weight depth: 23 (wmax) + 5 (w2)

// ws layout (bytes)
#define WS_CNT   0
#define WS_LIST  64
#define WS_S     65536       // S slices: 10*128*8640*4 = 44.2 MB (ws >= 66 MB, r1-r9)

// segment offsets: v-th segment holds [lin_v, Q_vv, Q_v,v+1, .., Q_v,15, pad0s]
// lengths (real) 17-v, padded to x4: {20,16,16,16,16,12,12,12,12,8,8,8,8,4,4,4}
#define SEG_OFF_INIT {0,20,36,52,68,84,96,108,120,132,140,148,156,164,168,172}

// ---------------------------------------------------------------------------
// Bucketing: bucket batch indices by element, pad each bucket to x64 by
// replicating the last real index (k_main then needs no load guards).
__device__ void do_lists(const float* __restrict__ y, int* __restrict__ cnt_g,
                         int* __restrict__ list_g, int t) {
    __shared__ int lcnt[E_];
    if (t < E_) lcnt[t] = 0;
    __syncthreads();
    for (int r = 0; r < 4; ++r) {
        int b = t + 256 * r;
        int e = 0;
        #pragma unroll
        for (int j = 1; j < E_; ++j)
            if (y[b * E_ + j] > 0.5f) e = j;
        int slot = atomicAdd(&lcnt[e], 1);
        list_g[e * B_ + slot] = b;
    }
    __syncthreads();
    if (t < E_) {
        int c0 = lcnt[t];
        cnt_g[t] = c0;
        int last = (c0 > 0) ? list_g[t * B_ + c0 - 1] : 0;
        int cp = (c0 + 63) & ~63;
        if (cp > B_) cp = B_;
        for (int s2 = c0; s2 < cp; ++s2) list_g[t * B_ + s2] = last;
    }
}

// ---------------------------------------------------------------------------
// k_s: build segment-layout S rows (UNCHANGED from verified r11/r12 version):
//  slot (v,0)   : lin_v  = sum_q U2[j,v,q]  * w2[e,q,c]
//  slot (v,l>0) : Q_v,i  = sum_k (U3[j,v,i,k] + (i!=v)*U3[j,i,v,k]) * wmax[e,k,c]
//                 with i = v+l-1; pad slots = 0.
__global__ __launch_bounds__(256, 2) void k_s(const float* __restrict__ U3,
                                              const float* __restrict__ U2,
                                              const float* __restrict__ wmax,
                                              const float* __restrict__ w2,
                                              const float* __restrict__ y,
                                              float* __restrict__ Sg,
                                              int* __restrict__ cnt_g,
                                              int* __restrict__ list_g) {
    const int t = threadIdx.x;
    if (blockIdx.x == 48) {
        if (blockIdx.y == 0 && blockIdx.z == 0) do_lists(y, cnt_g, list_g, t);
        return;
    }
    __shared__ __align__(16) float U3L[ELL * ELL * P3];  // 23,552 B
    __shared__ __align__(16) float wsm[KD * 32];         //  3,584 B

    const int j  = blockIdx.x;
    const int e  = blockIdx.y;
    const int cq = blockIdx.z;

    // stage U3[j] (5888 floats = 1472 f4), fully coalesced
    {
        const float4* src4 = (const float4*)(U3 + (size_t)j * (ELL * ELL * P3));
        float4* dst4 = (float4*)U3L;
        for (int f = t; f < 1472; f += 256) dst4[f] = src4[f];
    }
    // folded weight table (23 wmax + 5 w2) for this (e, c-quarter)
    for (int idx = t; idx < KD * 32; idx += 256) {
        int k = idx >> 5, cc = idx & 31, c = cq * 32 + cc;
        wsm[idx] = (k < 23) ? wmax[(e * P3 + k) * C_ + c]
                            : w2[(e * P2 + (k - 23)) * C_ + c];
    }
    __syncthreads();

    if (t >= NSEG) return;

    const int SO[16] = SEG_OFF_INIT;
    int v = 0;
    #pragma unroll
    for (int s = 1; s < 16; ++s) v += (t >= SO[s]) ? 1 : 0;
    const int l    = t - SO[v];
    const int real = 17 - v;           // slot count incl. lin

    float sk[P3], skl[P2];
    #pragma unroll
    for (int k = 0; k < P3; ++k) sk[k] = 0.f;
    #pragma unroll
    for (int q = 0; q < P2; ++q) skl[q] = 0.f;

    if (l == 0) {
        #pragma unroll
        for (int q = 0; q < P2; ++q)
            skl[q] = U2[(size_t)j * (ELL * P2) + v * P2 + q];
    } else if (l < real) {
        int i = v + l - 1;
        const float* pa = &U3L[(v * ELL + i) * P3];
        const float* pb = &U3L[(i * ELL + v) * P3];
        if (i != v) {
            #pragma unroll
            for (int k = 0; k < P3; ++k) sk[k] = pa[k] + pb[k];
        } else {
            #pragma unroll
            for (int k = 0; k < P3; ++k) sk[k] = pa[k];
        }
    }   // else: pad slot -> stays zero

    #pragma unroll
    for (int g = 0; g < 8; ++g) {
        float a[4] = {0.f, 0.f, 0.f, 0.f};
        #pragma unroll
        for (int k = 0; k < P3; ++k) {
            float4 wk = *(const float4*)&wsm[k * 32 + 4 * g];
            a[0] += sk[k] * wk.x; a[1] += sk[k] * wk.y;
            a[2] += sk[k] * wk.z; a[3] += sk[k] * wk.w;
        }
        #pragma unroll
        for (int q = 0; q < P2; ++q) {
            float4 wk = *(const float4*)&wsm[(23 + q) * 32 + 4 * g];
            a[0] += skl[q] * wk.x; a[1] += skl[q] * wk.y;
            a[2] += skl[q] * wk.z; a[3] += skl[q] * wk.w;
        }
        #pragma unroll
        for (int q2 = 0; q2 < 4; ++q2) {
            int c = cq * 32 + g * 4 + q2;
            Sg[(size_t)(e * C_ + c) * SRS + j * RSTR + t] = a[q2];
        }
    }
}

// ---------------------------------------------------------------------------
// k_main r14: EXACT r12 loop structure (single-chunk, __syncthreads() pin,
// 64-VGPR codegen verified at 46.5us / VALUBusy 83% / occupancy 33%) with ONE
// isolated change: the pad-trimmed v-loop from r13 (verified correct there).
//   - xm[4][19] -> xm[4][16]: the 3 zero pads and every FMA against a
//     known-zero coefficient are removed at compile time (compile-time index
//     guards after full unroll). ~17% fewer FMAs, 12 fewer live VGPRs.
// r13 post-mortem (57.4us REGRESSION): two-chunk pipeline doubled live regs
// (VGPR 64->120), halved occupancy (33->19%), VALUBusy fell 83->58%. With
// cnt~102 -> cntp~128 the chunk loop runs only ~2 iters/block, so the
// per-chunk barrier was never a cost; TLP (2.7 blocks/CU) was doing the
// latency hiding and the pipeline traded it away. Reverted.
// CRITICAL: __syncthreads() per chunk + unroll(disable) -- without them LICM
// hoists loop-invariant LDS reads -> VGPR blowup -> scratch spill (r5/r6).
__global__ __launch_bounds__(256, 2) void k_main(
    const float* __restrict__ x, const float* __restrict__ Sg,
    const float* __restrict__ U1, const float* __restrict__ w1,
    const int* __restrict__ cnt_g, const int* __restrict__ list_g,
    float* __restrict__ out) {

    __shared__ __align__(16) float V3L[16 * RSTR];   // 11,520 B

    const int t  = threadIdx.x;
    const int bx = blockIdx.x;
    const int w  = bx % 3, c = bx / 3;
    const int e  = blockIdx.y;
    const int xx = t & 15, bs = t >> 4;
    const int cnt  = cnt_g[e];
    const int cntp = (cnt + 63) & ~63;

    // ---- fill V3L: this w's 16 rows = 2880 floats = 720 f4, straight copy
    {
        const float4* src = (const float4*)(Sg + (size_t)(e * C_ + c) * SRS
                                            + (size_t)w * 16 * RSTR);
        float4* dst = (float4*)V3L;
        #pragma unroll
        for (int r = 0; r < 2; ++r) dst[t + 256 * r] = src[t + 256 * r];
        if (t < 208) dst[512 + t] = src[512 + t];
    }
    const float v1x = U1[w * 16 + xx] * w1[e * C_ + c];
    __syncthreads();

    const float* v3p = &V3L[xx * RSTR];
    const int SO[16] = SEG_OFF_INIT;

    // ---- chunk loop: 64 rows per chunk, 4 per thread ----
    #pragma clang loop unroll(disable)
    for (int base = 0; base < cntp; base += 64) {
        __syncthreads();   // anti-LICM liveness pin (see header note)

        const int slot = base + bs * 4;
        int bidx[4];
        #pragma unroll
        for (int r = 0; r < 4; ++r) bidx[r] = list_g[e * B_ + slot + r];

        float xm[4][16];
        float xo[4];
        #pragma unroll
        for (int r = 0; r < 4; ++r) {
            const float* xb = x + ((size_t)bidx[r] * C_ + c) * ELL;
            #pragma unroll
            for (int i4 = 0; i4 < 4; ++i4) {
                float4 a = ((const float4*)xb)[i4];
                xm[r][4 * i4 + 0] = a.x; xm[r][4 * i4 + 1] = a.y;
                xm[r][4 * i4 + 2] = a.z; xm[r][4 * i4 + 3] = a.w;
            }
            xo[r] = xb[xx];   // own-x element (L1 hit; no dynamic reg index)
        }

        float t2[4] = {0.f, 0.f, 0.f, 0.f};
        #pragma unroll
        for (int v = 0; v < 16; ++v) {
            const int off = SO[v];
            const int nf4 = (v == 0) ? 5 : (v < 5) ? 4 : (v < 9) ? 3 : (v < 13) ? 2 : 1;
            float inner[4];
            {   // first f4: [lin, Q_vv, Q_v,v+1, Q_v,v+2]
                float4 u = *(const float4*)(v3p + off);
                #pragma unroll
                for (int r = 0; r < 4; ++r) {
                    float s = u.x + u.y * xm[r][v];
                    if (v + 1 <= 15) s += u.z * xm[r][v + 1];
                    if (v + 2 <= 15) s += u.w * xm[r][v + 2];
                    inner[r] = s;
                }
            }
            #pragma unroll
            for (int q = 1; q < nf4; ++q) {
                float4 u = *(const float4*)(v3p + off + 4 * q);
                const int i0 = v + 4 * q - 1;
                #pragma unroll
                for (int r = 0; r < 4; ++r) {
                    inner[r] += u.x * xm[r][i0];
                    if (i0 + 1 <= 15) inner[r] += u.y * xm[r][i0 + 1];
                    if (i0 + 2 <= 15) inner[r] += u.z * xm[r][i0 + 2];
                    if (i0 + 3 <= 15) inner[r] += u.w * xm[r][i0 + 3];
                }
            }
            #pragma unroll
            for (int r = 0; r < 4; ++r) t2[r] += xm[r][v] * inner[r];
        }

        // out[b,c,w] = sum_xx (t2 + v1[xx]) * x[xx]  -- width-16 butterfly
        float cv[4];
        #pragma unroll
        for (int r = 0; r < 4; ++r) cv[r] = (t2[r] + v1x) * xo[r];
        #pragma unroll
        for (int m = 1; m < 16; m <<= 1) {
            #pragma unroll
            for (int r = 0; r < 4; ++r) cv[r] += __shfl_xor(cv[r], m, 16);
        }
        if (xx == 0) {
            #pragma unroll
            for (int r = 0; r < 4; ++r)
                if (slot + r < cnt)
                    out[(size_t)bidx[r] * (C_ * EQ) + c * EQ + w] = cv[r];
        }
    }
}

// ---------------------------------------------------------------------------
extern "C" void kernel_launch(void* const* d_in, const int* in_sizes, int n_in,
                              void* d_out, int out_size, void* d_ws, size_t ws_size,
                              hipStream_t stream) {
    const float* x    = (const float*)d_in[0];
    const float* y    = (const float*)d_in[1];
    const float* U3   = (const float*)d_in[2];
    const float* U2   = (const float*)d_in[3];
    const float* U1   = (const float*)d_in[4];
    const float* wmax = (const float*)d_in[5];
    const float* w2   = (const float*)d_in[6];
    const float* w1   = (const float*)d_in[7];
    float* out = (float*)d_out;
    char*  ws  = (char*)d_ws;

    int*   cnt_g  = (int*)(ws + WS_CNT);
    int*   list_g = (int*)(ws + WS_LIST);
    float* Sg     = (float*)(ws + WS_S);
    (void)ws_size;   // 44.3 MB needed; harness ws confirmed >= 66 MB (r1-r9)

    k_s<<<dim3(49, E_, 4), 256, 0, stream>>>(U3, U2, wmax, w2, y, Sg, cnt_g, list_g);
    k_main<<<dim3(C_ * EQ, E_), 256, 0, stream>>>(x, Sg, U1, w1, cnt_g, list_g, out);
}